// Round 1
// baseline (4344.040 us; speedup 1.0000x reference)
//
#include <hip/hip_runtime.h>
#include <math.h>

// TS2Vec hierarchical contrastive loss, fp32 baseline.
//
// Layout strategy: transpose z1,z2 to [B][L][C] (C=320 contiguous) once, then
// max-pool along L for 11 more depths (pool commutes with this layout).
// Both losses reduce to: per Gram-matrix row r: LSE_{m!=r}(Z_r . Z_m) - Z_r . Z_partner(r),
// scaled by 1/(16*L) per depth, summed over 12 depths, divided by 11.
//   temp: per (depth, b): M=2L rows = [z1t(b,:,:); z2t(b,:,:)]
//   inst: per (depth, l): 16 rows = vectors i=0..15 at zt[(i*L + l)*C]  (B=8 makes
//         z1/z2 indexing collapse to a single formula since z2t sits at +B*L*C)
//
// Workspace: ws[0..1] = {inst_sum, temp_sum}; ws+64 = pooled transposed tensors,
// 2*8*320*4095 floats ~= 84 MB.

#define B_DIM 8
#define C_DIM 320
#define T_DIM 2048
#define NDEPTH 12

// ---------------- tiny utility kernels ----------------
__global__ void zero_kernel(float* acc) {
  if (threadIdx.x < 2) acc[threadIdx.x] = 0.0f;
}

__global__ void finalize_kernel(const float* __restrict__ acc, float* __restrict__ out) {
  if (threadIdx.x == 0) {
    float inst = acc[0] * (1.0f / 11.0f);
    float temp = acc[1] * (1.0f / 11.0f);
    out[0] = 0.5f * inst + 0.5f * temp;   // ALPHA = 0.5
    out[1] = inst;
    out[2] = temp;
  }
}

// ---------------- transpose [B][C][T] -> [B][T][C] ----------------
__global__ __launch_bounds__(256) void transpose_kernel(const float* __restrict__ in,
                                                        float* __restrict__ out) {
  __shared__ float tile[32][33];
  const int b  = blockIdx.z;
  const int t0 = blockIdx.x * 32;
  const int c0 = blockIdx.y * 32;
  const int tx = threadIdx.x;   // 0..31
  const int ty = threadIdx.y;   // 0..7
#pragma unroll
  for (int k = 0; k < 4; ++k) {
    int c = c0 + ty + k * 8;
    tile[ty + k * 8][tx] = in[((long)b * C_DIM + c) * T_DIM + t0 + tx];
  }
  __syncthreads();
#pragma unroll
  for (int k = 0; k < 4; ++k) {
    int t = t0 + ty + k * 8;
    out[((long)b * T_DIM + t) * C_DIM + c0 + tx] = tile[tx][ty + k * 8];
  }
}

// ---------------- max-pool along L: [B][L][C] -> [B][L/2][C] ----------------
// blockIdx.y selects tensor (z1/z2).
__global__ __launch_bounds__(256) void pool_kernel(const float* __restrict__ in1,
                                                   float* __restrict__ out1,
                                                   const float* __restrict__ in2,
                                                   float* __restrict__ out2,
                                                   int Lout, int n) {
  const float* in  = blockIdx.y ? in2 : in1;
  float*       out = blockIdx.y ? out2 : out1;
  int idx = blockIdx.x * 256 + threadIdx.x;
  if (idx >= n) return;
  int c   = idx % C_DIM;
  int row = idx / C_DIM;          // b*Lout + l
  int b   = row / Lout;
  int l   = row % Lout;
  long base = (((long)b * (2 * Lout) + 2 * l) * C_DIM) + c;
  out[idx] = fmaxf(in[base], in[base + C_DIM]);
}

// ---------------- temp loss: per (b) 2L x 2L Gram with online LSE ----------------
// Block: 256 threads, 64x64 tile, 4x4 per thread.
// Thread grid: ty = tid>>4 (rows ty*4..), tx = tid&15 (cols tx*4..).
// Lanes sharing ty are 16 consecutive lanes -> row stats via __shfl_xor(1,2,4,8).
#define KB 32
#define LDK 36   // padded LDS row stride (floats); 36*4B keeps float4 alignment

__global__ __launch_bounds__(256) void temp_kernel(const float* __restrict__ zt,
                                                   int L, float* __restrict__ acc,
                                                   float scale) {
  __shared__ float As[64][LDK];
  __shared__ float Bs[64][LDK];
  __shared__ float red[4];

  const int M  = 2 * L;
  const int b  = blockIdx.y;
  const int r0 = blockIdx.x * 64;
  const int tid = threadIdx.x;
  const int tx = tid & 15;
  const int ty = tid >> 4;

  // loader mapping: 64 rows x 32 k = 512 float4; each thread loads 2 per buffer
  const int l_rr = tid >> 2;          // 0..63
  const int l_k4 = (tid & 3) * 4;     // 0,4,8,12

  // row -> element offset (clamped for out-of-range rows; results masked later)
  auto row_off = [&](int r) -> long {
    r = (r < M) ? r : (M - 1);
    int idx = (r < L) ? (b * L + r) : ((B_DIM + b) * L + (r - L));
    return (long)idx * C_DIM;
  };

  float mrow[4], srow[4], pos[4];
#pragma unroll
  for (int i = 0; i < 4; ++i) { mrow[i] = -INFINITY; srow[i] = 0.0f; pos[i] = 0.0f; }

  const long a_off = row_off(r0 + l_rr);
  const int ntiles = (M + 63) >> 6;

  for (int ct = 0; ct < ntiles; ++ct) {
    const int m0 = ct * 64;
    float accS[4][4];
#pragma unroll
    for (int i = 0; i < 4; ++i)
#pragma unroll
      for (int j = 0; j < 4; ++j) accS[i][j] = 0.0f;

    const long b_off = row_off(m0 + l_rr);

    for (int k0 = 0; k0 < C_DIM; k0 += KB) {
      __syncthreads();   // protect LDS from previous iteration's readers
      float4 av0 = *(const float4*)(zt + a_off + k0 + l_k4);
      float4 av1 = *(const float4*)(zt + a_off + k0 + l_k4 + 16);
      float4 bv0 = *(const float4*)(zt + b_off + k0 + l_k4);
      float4 bv1 = *(const float4*)(zt + b_off + k0 + l_k4 + 16);
      *(float4*)&As[l_rr][l_k4]      = av0;
      *(float4*)&As[l_rr][l_k4 + 16] = av1;
      *(float4*)&Bs[l_rr][l_k4]      = bv0;
      *(float4*)&Bs[l_rr][l_k4 + 16] = bv1;
      __syncthreads();
#pragma unroll
      for (int kk = 0; kk < KB; kk += 4) {
        float4 a[4], bb[4];
#pragma unroll
        for (int i = 0; i < 4; ++i) a[i]  = *(const float4*)&As[ty * 4 + i][kk];
#pragma unroll
        for (int j = 0; j < 4; ++j) bb[j] = *(const float4*)&Bs[tx * 4 + j][kk];
#pragma unroll
        for (int i = 0; i < 4; ++i)
#pragma unroll
          for (int j = 0; j < 4; ++j)
            accS[i][j] += a[i].x * bb[j].x + a[i].y * bb[j].y +
                          a[i].z * bb[j].z + a[i].w * bb[j].w;
      }
    }

    // online LSE update for this column tile (registers + wave shuffles only)
#pragma unroll
    for (int i = 0; i < 4; ++i) {
      const int gr  = r0 + ty * 4 + i;
      const int prt = (gr < L) ? (gr + L) : (gr - L);
      float v[4];
      float mloc = -INFINITY;
#pragma unroll
      for (int j = 0; j < 4; ++j) {
        int gc = m0 + tx * 4 + j;
        float s = accS[i][j];
        if (gr < M && gc == prt) pos[i] += s;    // positive captured exactly once
        bool valid = (gc < M) && (gc != gr);
        v[j] = valid ? s : -INFINITY;
        mloc = fmaxf(mloc, v[j]);
      }
#pragma unroll
      for (int msk = 1; msk < 16; msk <<= 1) mloc = fmaxf(mloc, __shfl_xor(mloc, msk));
      float mnew = fmaxf(mrow[i], mloc);
      float sloc = 0.0f;
#pragma unroll
      for (int j = 0; j < 4; ++j) sloc += expf(v[j] - mnew);   // exp(-inf)=0
#pragma unroll
      for (int msk = 1; msk < 16; msk <<= 1) sloc += __shfl_xor(sloc, msk);
      float f = expf(mrow[i] - mnew);                          // first tile: 0
      srow[i] = srow[i] * f + sloc;
      mrow[i] = mnew;
    }
  }

  // per-thread partial loss: row stats replicated across 16 tx-lanes -> tx==0 only
  float partial = 0.0f;
#pragma unroll
  for (int i = 0; i < 4; ++i) {
    int gr = r0 + ty * 4 + i;
    if (gr < M) {
      partial -= pos[i];
      if (tx == 0) partial += mrow[i] + logf(srow[i]);
    }
  }
#pragma unroll
  for (int msk = 1; msk < 64; msk <<= 1) partial += __shfl_xor(partial, msk);
  if ((tid & 63) == 0) red[tid >> 6] = partial;
  __syncthreads();
  if (tid == 0) atomicAdd(acc, (red[0] + red[1] + red[2] + red[3]) * scale);
}

// ---------------- inst loss: per (l) 16x16 Gram ----------------
#define LDA 324  // padded LDS row stride (floats), float4-aligned

__global__ __launch_bounds__(256) void inst_kernel(const float* __restrict__ zt,
                                                   int L, float* __restrict__ acc,
                                                   float scale) {
  __shared__ float Av[16][LDA];
  __shared__ float red[4];
  const int tid = threadIdx.x;
  const int i = tid >> 4;   // row 0..15
  const int j = tid & 15;   // col 0..15
  float partial = 0.0f;

  for (int l = blockIdx.x; l < L; l += gridDim.x) {
    __syncthreads();  // protect Av from previous iteration's readers
    // stage 16 vectors (16*320 floats), coalesced
#pragma unroll
    for (int k = 0; k < 20; ++k) {
      int e   = tid + 256 * k;
      int row = e / C_DIM;
      int c   = e - row * C_DIM;
      Av[row][c] = zt[((long)row * L + l) * C_DIM + c];
    }
    __syncthreads();

    float dot = 0.0f;
#pragma unroll 8
    for (int c = 0; c < C_DIM; c += 4) {
      float4 a = *(const float4*)&Av[i][c];
      float4 b = *(const float4*)&Av[j][c];
      dot += a.x * b.x + a.y * b.y + a.z * b.z + a.w * b.w;
    }

    const int prt = (i + 8) & 15;
    float ps = (j == prt) ? dot : 0.0f;
    float v  = (j == i) ? -INFINITY : dot;
    float mx = v;
#pragma unroll
    for (int msk = 1; msk < 16; msk <<= 1) mx = fmaxf(mx, __shfl_xor(mx, msk));
    float se = expf(v - mx);
#pragma unroll
    for (int msk = 1; msk < 16; msk <<= 1) {
      se += __shfl_xor(se, msk);
      ps += __shfl_xor(ps, msk);
    }
    if (j == 0) partial += mx + logf(se) - ps;
  }

#pragma unroll
  for (int msk = 1; msk < 64; msk <<= 1) partial += __shfl_xor(partial, msk);
  if ((tid & 63) == 0) red[tid >> 6] = partial;
  __syncthreads();
  if (tid == 0) atomicAdd(acc, (red[0] + red[1] + red[2] + red[3]) * scale);
}

// ---------------- launch ----------------
extern "C" void kernel_launch(void* const* d_in, const int* in_sizes, int n_in,
                              void* d_out, int out_size, void* d_ws, size_t ws_size,
                              hipStream_t stream) {
  const float* z1 = (const float*)d_in[0];
  const float* z2 = (const float*)d_in[1];
  float* out  = (float*)d_out;
  float* ws   = (float*)d_ws;
  float* acc  = ws;          // acc[0]=inst_sum, acc[1]=temp_sum
  float* base = ws + 64;

  static const int Ls[NDEPTH] = {2048, 1024, 512, 256, 128, 64, 32, 16, 8, 4, 2, 1};
  long off[NDEPTH];
  off[0] = 0;
  for (int d = 1; d < NDEPTH; ++d)
    off[d] = off[d - 1] + (long)2 * B_DIM * C_DIM * Ls[d - 1];

  zero_kernel<<<1, 64, 0, stream>>>(acc);

  // depth 0: transpose to [B][T][C]
  transpose_kernel<<<dim3(T_DIM / 32, C_DIM / 32, B_DIM), dim3(32, 8), 0, stream>>>(
      z1, base);
  transpose_kernel<<<dim3(T_DIM / 32, C_DIM / 32, B_DIM), dim3(32, 8), 0, stream>>>(
      z2, base + (long)B_DIM * T_DIM * C_DIM);

  // pooling chain
  for (int d = 1; d < NDEPTH; ++d) {
    int Lo = Ls[d];
    int n  = B_DIM * Lo * C_DIM;
    const float* in1 = base + off[d - 1];
    const float* in2 = in1 + (long)B_DIM * Ls[d - 1] * C_DIM;
    float* out1 = base + off[d];
    float* out2 = out1 + (long)B_DIM * Lo * C_DIM;
    pool_kernel<<<dim3((n + 255) / 256, 2), 256, 0, stream>>>(in1, out1, in2, out2, Lo, n);
  }

  // losses per depth
  for (int d = 0; d < NDEPTH; ++d) {
    int L = Ls[d];
    int M = 2 * L;
    float scale = 1.0f / (16.0f * (float)L);
    temp_kernel<<<dim3((M + 63) / 64, B_DIM), 256, 0, stream>>>(base + off[d], L,
                                                                acc + 1, scale);
    int gi = L < 512 ? L : 512;
    inst_kernel<<<dim3(gi), 256, 0, stream>>>(base + off[d], L, acc + 0, scale);
  }

  finalize_kernel<<<1, 64, 0, stream>>>(acc, out);
}

// Round 2
// 584.415 us; speedup vs baseline: 7.4331x; 7.4331x over previous
//
#include <hip/hip_runtime.h>
#include <math.h>

// TS2Vec hierarchical contrastive loss — bf16 MFMA version.
//
// Pipeline: transpose+convert [B][C][T]f32 -> pyramid depth0 [16][T][C]bf16
// (z1 batches 0..7, z2 batches 8..15), max-pool chain along L (11 launches),
// then ONE fused temp launch (all depths, MFMA flash-LSE) and ONE fused inst
// launch. Row loss = LSE_{c!=r}(S[r,c]) - S[r,partner]; scale 1/(16*L) per
// depth; outputs {0.5*(inst+temp), inst, temp}/11.
//
// temp kernel: block=128 rows, 4 waves x 32 rows. A-fragments (whole K=320)
// in registers: 2 subtiles x 10 ksteps x bf16x8 = 80 VGPRs, loaded once.
// Column tiles of 32 staged to LDS (padded stride 328 bf16 = 656B -> 2-way
// bank aliasing = free), double-buffered via register prefetch. Per tile per
// wave: 20 ds_read_b128 + 40 v_mfma_f32_16x16x32_bf16, then online-LSE
// epilogue (16-lane shuffle row reductions). S = Z Z^T is symmetric, so C/D
// row/col orientation cannot produce a wrong value, only a relabeling that
// the masks handle identically.

#define B_DIM 8
#define C_DIM 320
#define T_DIM 2048
#define NDEPTH 12

typedef __attribute__((ext_vector_type(8))) short bf16x8;
typedef __attribute__((ext_vector_type(4))) float f32x4;

__device__ inline float bf2f(unsigned short s) {
  unsigned u = ((unsigned)s) << 16;
  return __builtin_bit_cast(float, u);
}
__device__ inline unsigned short f2bf(float f) {
  unsigned u = __builtin_bit_cast(unsigned, f);
  u = (u + 0x7FFFu + ((u >> 16) & 1u)) >> 16;   // round-nearest-even
  return (unsigned short)u;
}

// ---------------- tiny utility kernels ----------------
__global__ void zero_kernel(float* acc) {
  if (threadIdx.x < 2) acc[threadIdx.x] = 0.0f;
}

__global__ void finalize_kernel(const float* __restrict__ acc, float* __restrict__ out) {
  if (threadIdx.x == 0) {
    float inst = acc[0] * (1.0f / 11.0f);
    float temp = acc[1] * (1.0f / 11.0f);
    out[0] = 0.5f * inst + 0.5f * temp;   // ALPHA = 0.5
    out[1] = inst;
    out[2] = temp;
  }
}

// ---------------- transpose+convert: [B][C][T]f32 -> [16][T][C]bf16 --------
__global__ __launch_bounds__(256) void transpose_kernel(const float* __restrict__ z1,
                                                        const float* __restrict__ z2,
                                                        unsigned short* __restrict__ out) {
  __shared__ float tile[32][33];
  const int zi = blockIdx.z >> 3;   // 0: z1, 1: z2
  const int b  = blockIdx.z & 7;
  const float* in = zi ? z2 : z1;
  const int t0 = blockIdx.x * 32;
  const int c0 = blockIdx.y * 32;
  const int tx = threadIdx.x;       // 0..31
  const int ty = threadIdx.y;       // 0..7
#pragma unroll
  for (int k = 0; k < 4; ++k) {
    int c = c0 + ty + k * 8;
    tile[ty + k * 8][tx] = in[((size_t)b * C_DIM + c) * T_DIM + t0 + tx];
  }
  __syncthreads();
#pragma unroll
  for (int k = 0; k < 4; ++k) {
    int t = t0 + ty + k * 8;
    out[((size_t)(zi * B_DIM + b) * T_DIM + t) * C_DIM + c0 + tx] = f2bf(tile[tx][ty + k * 8]);
  }
}

// ---------------- max-pool along L (bf16, x8 vectorized) -------------------
// Treats the depth array as [16][L][C]; pools L -> L/2.
__global__ __launch_bounds__(256) void pool_kernel(const unsigned short* __restrict__ in,
                                                   unsigned short* __restrict__ out,
                                                   int Lout, int n8) {
  int idx = blockIdx.x * 256 + threadIdx.x;
  if (idx >= n8) return;
  int e   = idx * 8;
  int c   = e % C_DIM;
  int row = e / C_DIM;            // bb*Lout + l, bb in [0,16)
  int bb  = row / Lout;
  int l   = row % Lout;
  size_t base = ((size_t)(bb * 2 * Lout + 2 * l)) * C_DIM + c;
  bf16x8 a = *(const bf16x8*)(in + base);
  bf16x8 b = *(const bf16x8*)(in + base + C_DIM);
  bf16x8 o;
#pragma unroll
  for (int k = 0; k < 8; ++k) {
    unsigned short ua = (unsigned short)a[k], ub = (unsigned short)b[k];
    o[k] = (short)(bf2f(ua) > bf2f(ub) ? ua : ub);
  }
  *(bf16x8*)(out + (size_t)e) = o;
}

// ---------------- fused temp loss (all depths), MFMA ----------------------
__global__ __launch_bounds__(256) void temp_kernel(const unsigned short* __restrict__ pyr,
                                                   float* __restrict__ acc) {
  constexpr int Ls[NDEPTH] = {2048, 1024, 512, 256, 128, 64, 32, 16, 8, 4, 2, 1};
  __shared__ unsigned short Bs[2][32][328];   // padded: 328*2B=656B stride
  __shared__ float red[4];

  // ---- decode (depth, batch, rowblock) from blockIdx ----
  int bid = blockIdx.x;
  int d = 0;
  size_t off = 0;
  for (;; ++d) {
    int Md = 2 * Ls[d];
    int nb = ((Md + 127) >> 7) * B_DIM;
    if (bid < nb) break;
    bid -= nb;
    off += (size_t)16 * Ls[d] * C_DIM;
  }
  const int L = Ls[d], M = 2 * L;
  const int b  = bid % B_DIM;         // batch = bid%8 -> XCD L2 affinity
  const int rb = bid / B_DIM;
  const int r0 = rb * 128;
  const float scale = 1.0f / (16.0f * (float)L);

  const unsigned short* Z = pyr + off;
  const int tid  = threadIdx.x;
  const int w    = tid >> 6;
  const int lane = tid & 63;
  const int lr   = lane & 15;         // col-within-subtile / A-row-within-subtile
  const int lg   = lane >> 4;         // k-group / C-row-group

  auto rowbase = [&](int r) -> const unsigned short* {
    r = (r < M) ? r : (M - 1);
    int idx = (r < L) ? (b * L + r) : ((B_DIM + b) * L + (r - L));
    return Z + (size_t)idx * C_DIM;
  };

  // ---- A fragments for this wave's 32 rows, whole K, in registers ----
  const int rwave = r0 + w * 32;
  bf16x8 afrag[2][10];
#pragma unroll
  for (int rs = 0; rs < 2; ++rs) {
    const unsigned short* rp = rowbase(rwave + rs * 16 + lr) + lg * 8;
#pragma unroll
    for (int ks = 0; ks < 10; ++ks)
      afrag[rs][ks] = *(const bf16x8*)(rp + ks * 32);
  }

  // ---- online-LSE state: rows (lg*4+reg) per subtile ----
  float m_[2][4], s_[2][4], p_[2][4];
#pragma unroll
  for (int rs = 0; rs < 2; ++rs)
#pragma unroll
    for (int rg = 0; rg < 4; ++rg) { m_[rs][rg] = -INFINITY; s_[rs][rg] = 0.0f; p_[rs][rg] = 0.0f; }

  const int ntiles = (M + 31) >> 5;
  bf16x8 pf[5];

  // prologue: stage column tile 0 into Bs[0]
#pragma unroll
  for (int i = 0; i < 5; ++i) {
    int ch = tid + 256 * i;           // 1280 chunks: 32 cols x 40 k-chunks
    int cc = ch / 40, kc = ch % 40;
    pf[i] = *(const bf16x8*)(rowbase(cc) + kc * 8);
    *(bf16x8*)&Bs[0][cc][kc * 8] = pf[i];
  }
  __syncthreads();

  for (int ct = 0; ct < ntiles; ++ct) {
    const int cur = ct & 1;
    const int c0  = ct * 32;

    // prefetch next tile into registers (overlaps with MFMA below)
    if (ct + 1 < ntiles) {
#pragma unroll
      for (int i = 0; i < 5; ++i) {
        int ch = tid + 256 * i;
        int cc = ch / 40, kc = ch % 40;
        pf[i] = *(const bf16x8*)(rowbase(c0 + 32 + cc) + kc * 8);
      }
    }

    // ---- compute 32x32 per wave: 20 ds_read_b128 + 40 MFMA ----
    f32x4 acc4[2][2];
#pragma unroll
    for (int rs = 0; rs < 2; ++rs)
#pragma unroll
      for (int cs = 0; cs < 2; ++cs) acc4[rs][cs] = (f32x4){0.f, 0.f, 0.f, 0.f};
#pragma unroll
    for (int ks = 0; ks < 10; ++ks) {
      bf16x8 b0 = *(const bf16x8*)&Bs[cur][lr][ks * 32 + lg * 8];
      bf16x8 b1 = *(const bf16x8*)&Bs[cur][16 + lr][ks * 32 + lg * 8];
      acc4[0][0] = __builtin_amdgcn_mfma_f32_16x16x32_bf16(afrag[0][ks], b0, acc4[0][0], 0, 0, 0);
      acc4[0][1] = __builtin_amdgcn_mfma_f32_16x16x32_bf16(afrag[0][ks], b1, acc4[0][1], 0, 0, 0);
      acc4[1][0] = __builtin_amdgcn_mfma_f32_16x16x32_bf16(afrag[1][ks], b0, acc4[1][0], 0, 0, 0);
      acc4[1][1] = __builtin_amdgcn_mfma_f32_16x16x32_bf16(afrag[1][ks], b1, acc4[1][1], 0, 0, 0);
    }

    // ---- online LSE epilogue; C/D layout: col=lane&15, row=lg*4+reg ----
#pragma unroll
    for (int rs = 0; rs < 2; ++rs) {
#pragma unroll
      for (int rg = 0; rg < 4; ++rg) {
        int gr  = rwave + rs * 16 + lg * 4 + rg;
        int prt = (gr < L) ? (gr + L) : (gr - L);
        int gc0 = c0 + lr, gc1 = c0 + 16 + lr;
        float v0 = acc4[rs][0][rg], v1 = acc4[rs][1][rg];
        if (gc0 == prt) p_[rs][rg] += v0;
        if (gc1 == prt) p_[rs][rg] += v1;
        float x0 = (gc0 < M && gc0 != gr) ? v0 : -INFINITY;
        float x1 = (gc1 < M && gc1 != gr) ? v1 : -INFINITY;
        float ml = fmaxf(x0, x1);
#pragma unroll
        for (int msk = 1; msk < 16; msk <<= 1) ml = fmaxf(ml, __shfl_xor(ml, msk));
        float mn = fmaxf(m_[rs][rg], ml);
        float sl = __expf(x0 - mn) + __expf(x1 - mn);   // exp(-inf)=0
#pragma unroll
        for (int msk = 1; msk < 16; msk <<= 1) sl += __shfl_xor(sl, msk);
        s_[rs][rg] = s_[rs][rg] * __expf(m_[rs][rg] - mn) + sl;
        m_[rs][rg] = mn;
      }
    }

    __syncthreads();                  // all waves done reading Bs[cur]
    if (ct + 1 < ntiles) {
#pragma unroll
      for (int i = 0; i < 5; ++i) {
        int ch = tid + 256 * i;
        int cc = ch / 40, kc = ch % 40;
        *(bf16x8*)&Bs[1 - cur][cc][kc * 8] = pf[i];
      }
    }
    __syncthreads();                  // stores visible before next compute
  }

  // ---- finish: loss = m + log(s) - pos per valid row ----
  float partial = 0.0f;
#pragma unroll
  for (int rs = 0; rs < 2; ++rs) {
#pragma unroll
    for (int rg = 0; rg < 4; ++rg) {
      float p = p_[rs][rg];
#pragma unroll
      for (int msk = 1; msk < 16; msk <<= 1) p += __shfl_xor(p, msk);
      int gr = rwave + rs * 16 + lg * 4 + rg;
      if (gr < M && lr == 0)
        partial += m_[rs][rg] + __logf(s_[rs][rg]) - p;
    }
  }
#pragma unroll
  for (int msk = 1; msk < 64; msk <<= 1) partial += __shfl_xor(partial, msk);
  if (lane == 0) red[w] = partial;
  __syncthreads();
  if (tid == 0) atomicAdd(acc, (red[0] + red[1] + red[2] + red[3]) * scale);
}

// ---------------- fused inst loss (all depths) ----------------------------
#define LDA 324  // padded fp32 LDS stride

__global__ __launch_bounds__(256) void inst_kernel(const unsigned short* __restrict__ pyr,
                                                   float* __restrict__ acc) {
  constexpr int Ls[NDEPTH] = {2048, 1024, 512, 256, 128, 64, 32, 16, 8, 4, 2, 1};
  __shared__ float Av[16][LDA];
  __shared__ float red[4];
  const int tid = threadIdx.x;
  const int i = tid >> 4;   // row 0..15
  const int j = tid & 15;   // col 0..15
  float partial = 0.0f;

  for (int gl = blockIdx.x; gl < 4095; gl += gridDim.x) {
    // decode (depth, l)
    int d = 0, l = gl;
    size_t off = 0;
    while (l >= Ls[d]) { off += (size_t)16 * Ls[d] * C_DIM; l -= Ls[d]; ++d; }
    const int L = Ls[d];
    const float scale = 1.0f / (16.0f * (float)L);
    const unsigned short* Z = pyr + off;

    __syncthreads();  // protect Av from previous iteration's readers
#pragma unroll
    for (int k = 0; k < 20; ++k) {
      int e   = tid + 256 * k;
      int row = e / C_DIM;
      int c   = e - row * C_DIM;
      Av[row][c] = bf2f(Z[((size_t)row * L + l) * C_DIM + c]);
    }
    __syncthreads();

    float dot = 0.0f;
#pragma unroll 8
    for (int c = 0; c < C_DIM; c += 4) {
      float4 a = *(const float4*)&Av[i][c];
      float4 b = *(const float4*)&Av[j][c];
      dot += a.x * b.x + a.y * b.y + a.z * b.z + a.w * b.w;
    }

    const int prt = (i + 8) & 15;
    float ps = (j == prt) ? dot : 0.0f;
    float v  = (j == i) ? -INFINITY : dot;
    float mx = v;
#pragma unroll
    for (int msk = 1; msk < 16; msk <<= 1) mx = fmaxf(mx, __shfl_xor(mx, msk));
    float se = __expf(v - mx);
#pragma unroll
    for (int msk = 1; msk < 16; msk <<= 1) {
      se += __shfl_xor(se, msk);
      ps += __shfl_xor(ps, msk);
    }
    if (j == 0) partial += (mx + __logf(se) - ps) * scale;
  }

#pragma unroll
  for (int msk = 1; msk < 64; msk <<= 1) partial += __shfl_xor(partial, msk);
  if ((tid & 63) == 0) red[tid >> 6] = partial;
  __syncthreads();
  if (tid == 0) atomicAdd(acc, red[0] + red[1] + red[2] + red[3]);
}

// ---------------- launch ----------------
extern "C" void kernel_launch(void* const* d_in, const int* in_sizes, int n_in,
                              void* d_out, int out_size, void* d_ws, size_t ws_size,
                              hipStream_t stream) {
  const float* z1 = (const float*)d_in[0];
  const float* z2 = (const float*)d_in[1];
  float* out = (float*)d_out;
  float* acc = (float*)d_ws;                              // acc[0]=inst, acc[1]=temp
  unsigned short* pyr = (unsigned short*)((char*)d_ws + 256);

  static const int Ls[NDEPTH] = {2048, 1024, 512, 256, 128, 64, 32, 16, 8, 4, 2, 1};

  zero_kernel<<<1, 64, 0, stream>>>(acc);

  transpose_kernel<<<dim3(T_DIM / 32, C_DIM / 32, 16), dim3(32, 8), 0, stream>>>(z1, z2, pyr);

  size_t off = 0;
  for (int d = 1; d < NDEPTH; ++d) {
    int Lo = Ls[d];
    const unsigned short* in = pyr + off;
    off += (size_t)16 * Ls[d - 1] * C_DIM;
    unsigned short* o = pyr + off;
    int n8 = 16 * Lo * C_DIM / 8;
    pool_kernel<<<dim3((n8 + 255) / 256), 256, 0, stream>>>(in, o, Lo, n8);
  }

  // fused temp: sum over depths of 8 * ceil(2L/128) blocks = 552
  int nblk = 0;
  for (int d = 0; d < NDEPTH; ++d) nblk += ((2 * Ls[d] + 127) / 128) * B_DIM;
  temp_kernel<<<dim3(nblk), 256, 0, stream>>>(pyr, acc + 1);

  inst_kernel<<<dim3(480), 256, 0, stream>>>(pyr, acc);

  finalize_kernel<<<1, 64, 0, stream>>>(acc, out);
}

// Round 4
// 465.897 us; speedup vs baseline: 9.3240x; 1.2544x over previous
//
#include <hip/hip_runtime.h>

// TS2Vec hierarchical contrastive loss — bf16 MFMA, flash-LSE, column-split.
//
// Pyramid: [16][L][C] bf16 per depth (z1 batches 0..7, z2 = 8..15), built by
// transpose+convert then 11 max-pool launches.
//
// temp: per (depth, batch): row loss = LSE_{c!=r}(S[r,c]) - S[r,partner],
// S = Z Z^T (M=2L rows, K=C=320). One fused launch, 1448 near-uniform blocks:
// depth0 col-split x4, depth1 x2 (balance). Block = 2 waves x 64 rows; A
// (whole K) in 160 VGPRs/wave; B tiles (32 cols) staged global->LDS via
// __builtin_amdgcn_global_load_lds into fragment-ordered 1KB blobs (lane-
// contiguous ds_read_b128, conflict-free), double-buffered. Online LSE is
// PER-LANE (no in-loop shuffles; 16-lane merge once at end). Per-row (m,s)
// partials written to ws; merge kernel folds column chunks. Positives are
// linear -> single per-lane accumulator -> one atomic per block.
//
// inst: per (depth,l) 16x16 Gram via 10 MFMA; A-frag == B-frag (S=ZZ^T).
// exp/log in base-2 via __builtin_amdgcn_{exp2f,logf} (v_exp_f32/v_log_f32);
// NOTE: do NOT use __exp2f/__log2f — they collide with glibc math.h reserved
// names under hipcc's g++ driver mode. exp2 args clamped >= -128 (NaN guard).

#define B_DIM 8
#define C_DIM 320
#define T_DIM 2048
#define NDEPTH 12
#define LOG2E 1.44269504088896340736f
#define LN2 0.69314718055994530942f
#define NEG_INF (-__builtin_inff())

typedef __attribute__((ext_vector_type(8))) short bf16x8;
typedef __attribute__((ext_vector_type(4))) float f32x4;

#define AS1 __attribute__((address_space(1)))
#define AS3 __attribute__((address_space(3)))

__device__ inline void gload_lds16(const void* g, void* l) {
  __builtin_amdgcn_global_load_lds((const AS1 unsigned int*)g, (AS3 unsigned int*)l,
                                   16, 0, 0);
}

__device__ inline float fast_exp2(float x) { return __builtin_amdgcn_exp2f(x); }
__device__ inline float fast_log2(float x) { return __builtin_amdgcn_logf(x); }

__device__ inline float bf2f(unsigned short s) {
  unsigned u = ((unsigned)s) << 16;
  return __builtin_bit_cast(float, u);
}
__device__ inline unsigned short f2bf(float f) {
  unsigned u = __builtin_bit_cast(unsigned, f);
  u = (u + 0x7FFFu + ((u >> 16) & 1u)) >> 16;  // round-nearest-even
  return (unsigned short)u;
}

// ---------------- tiny utility kernels ----------------
__global__ void zero_kernel(float* acc) {
  if (threadIdx.x < 2) acc[threadIdx.x] = 0.0f;
}

__global__ void finalize_kernel(const float* __restrict__ acc, float* __restrict__ out) {
  if (threadIdx.x == 0) {
    float inst = acc[0] * (1.0f / 11.0f);
    float temp = acc[1] * (1.0f / 11.0f);
    out[0] = 0.5f * inst + 0.5f * temp;  // ALPHA = 0.5
    out[1] = inst;
    out[2] = temp;
  }
}

// ---------------- transpose+convert: [B][C][T]f32 -> [16][T][C]bf16 --------
__global__ __launch_bounds__(256) void transpose_kernel(const float* __restrict__ z1,
                                                        const float* __restrict__ z2,
                                                        unsigned short* __restrict__ out) {
  __shared__ float tile[32][33];
  const int zi = blockIdx.z >> 3;
  const int b = blockIdx.z & 7;
  const float* in = zi ? z2 : z1;
  const int t0 = blockIdx.x * 32;
  const int c0 = blockIdx.y * 32;
  const int tx = threadIdx.x;
  const int ty = threadIdx.y;
#pragma unroll
  for (int k = 0; k < 4; ++k) {
    int c = c0 + ty + k * 8;
    tile[ty + k * 8][tx] = in[((size_t)b * C_DIM + c) * T_DIM + t0 + tx];
  }
  __syncthreads();
#pragma unroll
  for (int k = 0; k < 4; ++k) {
    int t = t0 + ty + k * 8;
    out[((size_t)(zi * B_DIM + b) * T_DIM + t) * C_DIM + c0 + tx] = f2bf(tile[tx][ty + k * 8]);
  }
}

// ---------------- max-pool along L (bf16 x8) ------------------------------
__global__ __launch_bounds__(256) void pool_kernel(const unsigned short* __restrict__ in,
                                                   unsigned short* __restrict__ out,
                                                   int Lout, int n8) {
  int idx = blockIdx.x * 256 + threadIdx.x;
  if (idx >= n8) return;
  int e = idx * 8;
  int c = e % C_DIM;
  int row = e / C_DIM;
  int bb = row / Lout;
  int l = row % Lout;
  size_t base = ((size_t)(bb * 2 * Lout + 2 * l)) * C_DIM + c;
  bf16x8 a = *(const bf16x8*)(in + base);
  bf16x8 b = *(const bf16x8*)(in + base + C_DIM);
  bf16x8 o;
#pragma unroll
  for (int k = 0; k < 8; ++k) {
    unsigned short ua = (unsigned short)a[k], ub = (unsigned short)b[k];
    o[k] = (short)(bf2f(ua) > bf2f(ub) ? ua : ub);
  }
  *(bf16x8*)(out + (size_t)e) = o;
}

// ---------------- fused temp loss: partials over column chunks ------------
__global__ __launch_bounds__(128, 2) void temp_kernel(const unsigned short* __restrict__ pyr,
                                                      float2* __restrict__ ent,
                                                      float* __restrict__ acc) {
  constexpr int Ls[NDEPTH] = {2048, 1024, 512, 256, 128, 64, 32, 16, 8, 4, 2, 1};
  constexpr int SP[NDEPTH] = {4, 2, 1, 1, 1, 1, 1, 1, 1, 1, 1, 1};
  constexpr int NB[NDEPTH] = {1024, 256, 64, 32, 16, 8, 8, 8, 8, 8, 8, 8};
  constexpr size_t ZOFF[NDEPTH] = {0,        10485760, 15728640, 18350080,
                                   19660800, 20316160, 20643840, 20807680,
                                   20889600, 20930560, 20951040, 20961280};
  constexpr size_t EBASE[NDEPTH] = {0,      131072, 163840, 172032, 176128, 178176,
                                    179200, 179712, 179968, 180096, 180160, 180192};
  constexpr float SCL[NDEPTH] = {
      1.f / (16 * 2048.f), 1.f / (16 * 1024.f), 1.f / (16 * 512.f), 1.f / (16 * 256.f),
      1.f / (16 * 128.f),  1.f / (16 * 64.f),   1.f / (16 * 32.f),  1.f / (16 * 16.f),
      1.f / (16 * 8.f),    1.f / (16 * 4.f),    1.f / (16 * 2.f),   1.f / (16 * 1.f)};

  __shared__ __align__(16) unsigned short Bs[2 * 10240];  // 2 bufs x 20 blobs x 1KB
  __shared__ float red[2];

  int bid = blockIdx.x;
  int d = 0;
  while (bid >= NB[d]) { bid -= NB[d]; ++d; }
  const int L = Ls[d], M = 2 * L, sp = SP[d];
  const int csz = M / sp;
  const int ntiles = (csz + 31) >> 5;
  const int b = bid & 7;  // batch fastest -> XCD L2 affinity
  const int t2 = bid >> 3;
  const int chunk = t2 % sp;
  const int rb = t2 / sp;
  const int r0 = rb * 128;
  const int cbase = chunk * csz;
  const float scale = SCL[d];
  const unsigned short* Z = pyr + ZOFF[d];

  const int tid = threadIdx.x;
  const int w = tid >> 6, lane = tid & 63;
  const int lr = lane & 15, lg = lane >> 4;

  auto rowptr = [&](int r) -> const unsigned short* {
    r = (r < M) ? r : (M - 1);
    int idx = (r < L) ? (b * L + r) : ((B_DIM + b) * L + (r - L));
    return Z + (size_t)idx * C_DIM;
  };

  // stage column tile ct into buffer buf: wave w does blobs ks in [5w,5w+5)x2
  auto stage = [&](int buf, int ct) {
    const int c0 = cbase + ct * 32;
#pragma unroll
    for (int i = 0; i < 5; ++i) {
      int ks = w * 5 + i;
#pragma unroll
      for (int sub = 0; sub < 2; ++sub) {
        const unsigned short* g = rowptr(c0 + sub * 16 + lr) + ks * 32 + lg * 8;
        gload_lds16(g, &Bs[buf * 10240 + (ks * 2 + sub) * 512]);
      }
    }
  };

  // A fragments: this wave's 64 rows, whole K, in registers (160 VGPR)
  const int rwave = r0 + w * 64;
  bf16x8 afrag[4][10];
#pragma unroll
  for (int rs = 0; rs < 4; ++rs) {
    const unsigned short* rp = rowptr(rwave + rs * 16 + lr) + lg * 8;
#pragma unroll
    for (int ks = 0; ks < 10; ++ks) afrag[rs][ks] = *(const bf16x8*)(rp + ks * 32);
  }

  // per-lane online LSE state (base-2): lane owns cols == lr (mod 16)
  float m_[4][4], s_[4][4];
  float pacc = 0.f;
#pragma unroll
  for (int rs = 0; rs < 4; ++rs)
#pragma unroll
    for (int rg = 0; rg < 4; ++rg) { m_[rs][rg] = NEG_INF; s_[rs][rg] = 0.f; }

  stage(0, 0);
  __syncthreads();

  for (int ct = 0; ct < ntiles; ++ct) {
    const int cur = ct & 1;
    if (ct + 1 < ntiles) stage(1 - cur, ct + 1);  // async into other buffer

    f32x4 c4[4][2];
#pragma unroll
    for (int rs = 0; rs < 4; ++rs)
#pragma unroll
      for (int cs = 0; cs < 2; ++cs) c4[rs][cs] = (f32x4){0.f, 0.f, 0.f, 0.f};

#pragma unroll
    for (int ks = 0; ks < 10; ++ks) {
      bf16x8 b0 = *(const bf16x8*)&Bs[cur * 10240 + (ks * 2 + 0) * 512 + lane * 8];
      bf16x8 b1 = *(const bf16x8*)&Bs[cur * 10240 + (ks * 2 + 1) * 512 + lane * 8];
#pragma unroll
      for (int rs = 0; rs < 4; ++rs) {
        c4[rs][0] = __builtin_amdgcn_mfma_f32_16x16x32_bf16(afrag[rs][ks], b0, c4[rs][0], 0, 0, 0);
        c4[rs][1] = __builtin_amdgcn_mfma_f32_16x16x32_bf16(afrag[rs][ks], b1, c4[rs][1], 0, 0, 0);
      }
    }

    // per-lane online LSE update: NO cross-lane ops here
    const int gc0 = cbase + ct * 32 + lr;
    const int gc1 = gc0 + 16;
#pragma unroll
    for (int rs = 0; rs < 4; ++rs) {
#pragma unroll
      for (int rg = 0; rg < 4; ++rg) {
        int gr = rwave + rs * 16 + lg * 4 + rg;
        int prt = (gr < L) ? (gr + L) : (gr - L);
        float v0 = c4[rs][0][rg], v1 = c4[rs][1][rg];
        if (gr < M) {
          if (gc0 == prt) pacc += v0;
          if (gc1 == prt) pacc += v1;
        }
        float x0 = (gc0 < M && gc0 != gr) ? v0 * LOG2E : NEG_INF;
        float x1 = (gc1 < M && gc1 != gr) ? v1 * LOG2E : NEG_INF;
        float mn = fmaxf(m_[rs][rg], fmaxf(x0, x1));
        s_[rs][rg] = s_[rs][rg] * fast_exp2(fmaxf(m_[rs][rg] - mn, -128.f)) +
                     fast_exp2(fmaxf(x0 - mn, -128.f)) + fast_exp2(fmaxf(x1 - mn, -128.f));
        m_[rs][rg] = mn;
      }
    }
    __syncthreads();  // buf[cur] reads done AND staged loads drained
  }

  // merge (m,s) across 16 lr-lanes (same row), write per-row-chunk partial
#pragma unroll
  for (int rs = 0; rs < 4; ++rs) {
#pragma unroll
    for (int rg = 0; rg < 4; ++rg) {
      float m = m_[rs][rg], s = s_[rs][rg];
      float mt = m;
#pragma unroll
      for (int k = 1; k < 16; k <<= 1) mt = fmaxf(mt, __shfl_xor(mt, k));
      float st = s * fast_exp2(fmaxf(m - mt, -128.f));
#pragma unroll
      for (int k = 1; k < 16; k <<= 1) st += __shfl_xor(st, k);
      int gr = rwave + rs * 16 + lg * 4 + rg;
      if (gr < M && lr == 0)
        ent[EBASE[d] + ((size_t)(b * M + gr)) * sp + chunk] = make_float2(mt, st);
    }
  }

  // positives are linear: one block-sum, one atomic
#pragma unroll
  for (int k = 1; k < 64; k <<= 1) pacc += __shfl_xor(pacc, k);
  if (lane == 0) red[w] = pacc;
  __syncthreads();
  if (tid == 0) atomicAdd(acc + 1, -(red[0] + red[1]) * scale);
}

// ---------------- merge column-chunk partials -> temp loss ----------------
__global__ __launch_bounds__(256) void merge_kernel(const float2* __restrict__ ent,
                                                    float* __restrict__ acc) {
  constexpr int Ls[NDEPTH] = {2048, 1024, 512, 256, 128, 64, 32, 16, 8, 4, 2, 1};
  constexpr int SP[NDEPTH] = {4, 2, 1, 1, 1, 1, 1, 1, 1, 1, 1, 1};
  constexpr size_t EBASE[NDEPTH] = {0,      131072, 163840, 172032, 176128, 178176,
                                    179200, 179712, 179968, 180096, 180160, 180192};
  constexpr int RBASE[NDEPTH] = {0,     32768, 49152, 57344, 61440, 63488,
                                 64512, 65024, 65280, 65408, 65472, 65504};
  __shared__ float red[4];
  int i = blockIdx.x * 256 + threadIdx.x;
  float partial = 0.f;
  if (i < 65520) {
    int d = 0;
    while (d < 11 && i >= RBASE[d + 1]) ++d;
    int rem = i - RBASE[d];
    int sp = SP[d];
    const float2* e = ent + EBASE[d] + (size_t)rem * sp;
    float mt = NEG_INF;
    for (int c = 0; c < sp; ++c) mt = fmaxf(mt, e[c].x);
    float st = 0.f;
    for (int c = 0; c < sp; ++c) st += e[c].y * fast_exp2(fmaxf(e[c].x - mt, -128.f));
    partial = (mt + fast_log2(st)) * (LN2 / 16.f) / (float)Ls[d];
  }
#pragma unroll
  for (int k = 1; k < 64; k <<= 1) partial += __shfl_xor(partial, k);
  if ((threadIdx.x & 63) == 0) red[threadIdx.x >> 6] = partial;
  __syncthreads();
  if (threadIdx.x == 0) atomicAdd(acc + 1, red[0] + red[1] + red[2] + red[3]);
}

// ---------------- fused inst loss: 16x16 Gram via MFMA --------------------
__global__ __launch_bounds__(256) void inst_kernel(const unsigned short* __restrict__ pyr,
                                                   float* __restrict__ acc) {
  constexpr int Ls[NDEPTH] = {2048, 1024, 512, 256, 128, 64, 32, 16, 8, 4, 2, 1};
  constexpr size_t ZOFF[NDEPTH] = {0,        10485760, 15728640, 18350080,
                                   19660800, 20316160, 20643840, 20807680,
                                   20889600, 20930560, 20951040, 20961280};
  constexpr float SCL[NDEPTH] = {
      1.f / (16 * 2048.f), 1.f / (16 * 1024.f), 1.f / (16 * 512.f), 1.f / (16 * 256.f),
      1.f / (16 * 128.f),  1.f / (16 * 64.f),   1.f / (16 * 32.f),  1.f / (16 * 16.f),
      1.f / (16 * 8.f),    1.f / (16 * 4.f),    1.f / (16 * 2.f),   1.f / (16 * 1.f)};
  __shared__ float red[4];
  const int tid = threadIdx.x;
  const int w = tid >> 6, lane = tid & 63, lr = lane & 15, lg = lane >> 4;
  const int gw = blockIdx.x * 4 + w;
  const int nw = gridDim.x * 4;
  float partial = 0.f;

  for (int gl = gw; gl < 4095; gl += nw) {
    int d = 0, l = gl;
    while (l >= Ls[d]) { l -= Ls[d]; ++d; }
    const int L = Ls[d];
    const unsigned short* Z = pyr + ZOFF[d];

    // fragment: row=lr, k=lg*8 + ks*32; same register serves A and B (S=ZZ^T)
    const unsigned short* rp = Z + ((size_t)lr * L + l) * C_DIM + lg * 8;
    bf16x8 fr[10];
#pragma unroll
    for (int ks = 0; ks < 10; ++ks) fr[ks] = *(const bf16x8*)(rp + ks * 32);
    f32x4 c4 = (f32x4){0.f, 0.f, 0.f, 0.f};
#pragma unroll
    for (int ks = 0; ks < 10; ++ks)
      c4 = __builtin_amdgcn_mfma_f32_16x16x32_bf16(fr[ks], fr[ks], c4, 0, 0, 0);

#pragma unroll
    for (int rg = 0; rg < 4; ++rg) {
      int gr = lg * 4 + rg, gc = lr;
      float v = c4[rg];
      int prt = (gr + 8) & 15;
      float ps = (gc == prt) ? v : 0.f;
      float x = (gc != gr) ? v * LOG2E : NEG_INF;
      float mx = x;
#pragma unroll
      for (int k = 1; k < 16; k <<= 1) mx = fmaxf(mx, __shfl_xor(mx, k));
      float se = fast_exp2(fmaxf(x - mx, -128.f));
#pragma unroll
      for (int k = 1; k < 16; k <<= 1) {
        se += __shfl_xor(se, k);
        ps += __shfl_xor(ps, k);
      }
      if (lr == 0) partial += ((mx + fast_log2(se)) * LN2 - ps) * SCL[d];
    }
  }

#pragma unroll
  for (int k = 1; k < 64; k <<= 1) partial += __shfl_xor(partial, k);
  if ((tid & 63) == 0) red[tid >> 6] = partial;
  __syncthreads();
  if (tid == 0) atomicAdd(acc, red[0] + red[1] + red[2] + red[3]);
}

// ---------------- launch ----------------
extern "C" void kernel_launch(void* const* d_in, const int* in_sizes, int n_in,
                              void* d_out, int out_size, void* d_ws, size_t ws_size,
                              hipStream_t stream) {
  const float* z1 = (const float*)d_in[0];
  const float* z2 = (const float*)d_in[1];
  float* out = (float*)d_out;
  float* acc = (float*)d_ws;                               // [0]=inst, [1]=temp
  float2* ent = (float2*)((char*)d_ws + 256);              // 180208 used, pad 180224
  unsigned short* pyr = (unsigned short*)((char*)d_ws + 256 + (size_t)180224 * 8);

  static const int Ls[NDEPTH] = {2048, 1024, 512, 256, 128, 64, 32, 16, 8, 4, 2, 1};

  zero_kernel<<<1, 64, 0, stream>>>(acc);

  transpose_kernel<<<dim3(T_DIM / 32, C_DIM / 32, 16), dim3(32, 8), 0, stream>>>(z1, z2, pyr);

  size_t off = 0;
  for (int d = 1; d < NDEPTH; ++d) {
    int Lo = Ls[d];
    const unsigned short* in = pyr + off;
    off += (size_t)16 * Ls[d - 1] * C_DIM;
    unsigned short* o = pyr + off;
    int n8 = 16 * Lo * C_DIM / 8;
    pool_kernel<<<dim3((n8 + 255) / 256), 256, 0, stream>>>(in, o, Lo, n8);
  }

  temp_kernel<<<dim3(1448), 128, 0, stream>>>(pyr, ent, acc);
  inst_kernel<<<dim3(256), 256, 0, stream>>>(pyr, acc);
  merge_kernel<<<dim3(256), 256, 0, stream>>>(ent, acc);

  finalize_kernel<<<1, 64, 0, stream>>>(acc, out);
}